// Round 2
// baseline (3113.050 us; speedup 1.0000x reference)
//
#include <hip/hip_runtime.h>
#include <math.h>

#define N_NODES 100000
#define IN_DIM 64
#define HID 128
#define HID2 64
#define N_EDGES 1600000
#define BN_EPS 1e-5f

// ---------------------------------------------------------------------------
// Edge aggregation: thread per (edge, 16B quad). 16 threads per edge.
//   agg[dst][q*4+i] += feat[src][q*4+i]
// float4 gather (coalesced 64B per 4 threads), 4 scalar atomics per thread.
// ---------------------------------------------------------------------------
__global__ __launch_bounds__(256) void edge_agg16(
    const float4* __restrict__ feat4,  // [N,16] float4  (= [N,64] float)
    const int* __restrict__ src,       // [E]
    const int* __restrict__ dst,       // [E]
    float* __restrict__ agg,           // [N,64]
    float* __restrict__ cnt,           // [N] or nullptr
    int nEdges)
{
    unsigned tid = blockIdx.x * 256u + threadIdx.x;
    int e = (int)(tid >> 4);
    if (e >= nEdges) return;
    int q = (int)(tid & 15);
    int s = src[e];
    int d = dst[e];
    float4 v = feat4[(size_t)s * 16 + q];
    float* ap = &agg[(size_t)d * 64 + q * 4];
    atomicAdd(ap + 0, v.x);
    atomicAdd(ap + 1, v.y);
    atomicAdd(ap + 2, v.z);
    atomicAdd(ap + 3, v.w);
    if (cnt != nullptr && q == 0) atomicAdd(&cnt[d], 1.0f);
}

// ---------------------------------------------------------------------------
// node1: per block of 64 nodes (256 threads = 4 waves):
//   stage mean (= agg1/cnt) and x tiles in LDS (padded, conflict-free)
//   h1 = relu(bn1(mean@W1_l + b1_l + x@W1_r))        -> kept in LDS only
//   t1 = h1@W2_l   (layer-2 aggregation operand)
//   r1 = h1@W2_r   (layer-2 root term, so node2 needs no GEMM)
// lane = node, wave w owns a 32-wide output slice. Weight rows are
// wave-uniform -> scalar loads. LDS rows padded (65/129) -> conflict-free.
// ---------------------------------------------------------------------------
__global__ __launch_bounds__(256, 2) void node1_kernel(
    const float* __restrict__ x,      // [N,64]
    const float* __restrict__ agg1,   // [N,64]
    const float* __restrict__ cnt,    // [N]
    const float* __restrict__ W1l,    // [64,128]
    const float* __restrict__ b1l,    // [128]
    const float* __restrict__ W1r,    // [64,128]
    const float* __restrict__ g1, const float* __restrict__ be1,
    const float* __restrict__ m1, const float* __restrict__ v1,
    const float* __restrict__ W2l,    // [128,64]
    const float* __restrict__ W2r,    // [128,64]
    float* __restrict__ t1,           // [N,64]
    float* __restrict__ r1)           // [N,64]
{
    __shared__ float sm[64][65];   // mean tile   (reused for t1 out-tile)
    __shared__ float sx[64][65];   // x tile      (reused for r1 out-tile)
    __shared__ float sh[64][129];  // h1 tile

    const int n0   = blockIdx.x * 64;
    const int t    = threadIdx.x;
    const int wave = t >> 6;
    const int lane = t & 63;

    // ---- stage: thread t handles node n0 + t/4, quad q = t&3 (16 floats) ----
    {
        const int r = t >> 2;          // local node row 0..63
        const int q = t & 3;
        const int nn = n0 + r;
        if (nn < N_NODES) {
            float inv = 1.0f / fmaxf(cnt[nn], 1.0f);
            const float4* a4 = (const float4*)(agg1 + (size_t)nn * 64);
            const float4* x4 = (const float4*)(x    + (size_t)nn * 64);
            #pragma unroll
            for (int i = 0; i < 4; ++i) {
                float4 av = a4[q * 4 + i];
                float4 xv = x4[q * 4 + i];
                int kb = q * 16 + i * 4;
                sm[r][kb + 0] = av.x * inv;
                sm[r][kb + 1] = av.y * inv;
                sm[r][kb + 2] = av.z * inv;
                sm[r][kb + 3] = av.w * inv;
                sx[r][kb + 0] = xv.x;
                sx[r][kb + 1] = xv.y;
                sx[r][kb + 2] = xv.z;
                sx[r][kb + 3] = xv.w;
            }
        } else {
            #pragma unroll
            for (int i = 0; i < 16; ++i) {
                sm[r][q * 16 + i] = 0.0f;
                sx[r][q * 16 + i] = 0.0f;
            }
        }
    }
    __syncthreads();

    // ---- h1 = relu(bn1(mean@W1l + b1l + x@W1r)); wave w -> j in [32w,32w+32) ----
    {
        const int jb = wave * 32;
        float acc[32];
        #pragma unroll
        for (int i = 0; i < 32; ++i) acc[i] = b1l[jb + i];
        #pragma unroll 2
        for (int k = 0; k < 64; ++k) {
            float mk = sm[lane][k];
            float xk = sx[lane][k];
            const float* wl = &W1l[k * HID + jb];
            const float* wr = &W1r[k * HID + jb];
            #pragma unroll
            for (int i = 0; i < 32; ++i) {
                acc[i] = fmaf(mk, wl[i], acc[i]);
                acc[i] = fmaf(xk, wr[i], acc[i]);
            }
        }
        #pragma unroll
        for (int i = 0; i < 32; ++i) {
            int j = jb + i;
            float s = g1[j] * rsqrtf(v1[j] + BN_EPS);
            sh[lane][j] = fmaxf((acc[i] - m1[j]) * s + be1[j], 0.0f);
        }
    }
    __syncthreads();

    // ---- t1 (waves 0,1) / r1 (waves 2,3): 32 outputs per wave over K=128 ----
    {
        const float* W = (wave < 2) ? W2l : W2r;
        const int ob = (wave & 1) * 32;
        float acc[32];
        #pragma unroll
        for (int i = 0; i < 32; ++i) acc[i] = 0.0f;
        #pragma unroll 2
        for (int k = 0; k < 128; ++k) {
            float hk = sh[lane][k];
            const float* wr = &W[k * HID2 + ob];
            #pragma unroll
            for (int i = 0; i < 32; ++i) acc[i] = fmaf(hk, wr[i], acc[i]);
        }
        __syncthreads();   // stage tiles (sm/sx) fully consumed; safe to reuse
        float* Tt = (wave < 2) ? &sm[0][0] : &sx[0][0];
        #pragma unroll
        for (int i = 0; i < 32; ++i) Tt[lane * 65 + ob + i] = acc[i];
    }
    __syncthreads();

    // ---- coalesced write of t1/r1 tiles ----
    {
        const int r = t >> 2;
        const int q = t & 3;
        const int nn = n0 + r;
        if (nn < N_NODES) {
            #pragma unroll
            for (int i = 0; i < 4; ++i) {
                int kb = q * 16 + i * 4;
                float4 tv = make_float4(sm[r][kb], sm[r][kb + 1], sm[r][kb + 2], sm[r][kb + 3]);
                float4 rv = make_float4(sx[r][kb], sx[r][kb + 1], sx[r][kb + 2], sx[r][kb + 3]);
                *(float4*)(t1 + (size_t)nn * 64 + kb) = tv;
                *(float4*)(r1 + (size_t)nn * 64 + kb) = rv;
            }
        }
    }
}

// ---------------------------------------------------------------------------
// node2: one wave per node; pure elementwise + 2-logit reduce.
//   h2 = relu(bn2(agg2/cnt + b2l + r1));  out = h2@Wc + bc
// ---------------------------------------------------------------------------
__global__ __launch_bounds__(256) void node2_kernel(
    const float* __restrict__ agg2,   // [N,64]  sum of t1 over in-edges
    const float* __restrict__ r1,     // [N,64]  h1@W2_r
    const float* __restrict__ cnt,    // [N]
    const float* __restrict__ b2l,    // [64]
    const float* __restrict__ g2, const float* __restrict__ be2,
    const float* __restrict__ m2, const float* __restrict__ v2,
    const float* __restrict__ Wc,     // [64,2]
    const float* __restrict__ bc,     // [2]
    float* __restrict__ out)          // [N,2]
{
    int node = (int)((blockIdx.x * 256u + threadIdx.x) >> 6);
    int lane = threadIdx.x & 63;
    if (node >= N_NODES) return;

    float inv = 1.0f / fmaxf(cnt[node], 1.0f);
    float pre = agg2[(size_t)node * 64 + lane] * inv + b2l[lane]
              + r1[(size_t)node * 64 + lane];
    float s  = g2[lane] * rsqrtf(v2[lane] + BN_EPS);
    float h2 = fmaxf((pre - m2[lane]) * s + be2[lane], 0.0f);

    float l0 = h2 * Wc[lane * 2 + 0];
    float l1 = h2 * Wc[lane * 2 + 1];
    #pragma unroll
    for (int off = 32; off > 0; off >>= 1) {
        l0 += __shfl_xor(l0, off);
        l1 += __shfl_xor(l1, off);
    }
    if (lane == 0) {
        out[(size_t)node * 2 + 0] = l0 + bc[0];
        out[(size_t)node * 2 + 1] = l1 + bc[1];
    }
}

// ---------------------------------------------------------------------------
extern "C" void kernel_launch(void* const* d_in, const int* in_sizes, int n_in,
                              void* d_out, int out_size, void* d_ws, size_t ws_size,
                              hipStream_t stream)
{
    const float* x    = (const float*)d_in[0];
    const int*   eidx = (const int*)d_in[1];   // [2, E]: row 0 = src, row 1 = dst
    const float* W1l  = (const float*)d_in[2];
    const float* b1l  = (const float*)d_in[3];
    const float* W1r  = (const float*)d_in[4];
    const float* W2l  = (const float*)d_in[5];
    const float* b2l  = (const float*)d_in[6];
    const float* W2r  = (const float*)d_in[7];
    const float* g1   = (const float*)d_in[8];
    const float* be1  = (const float*)d_in[9];
    const float* m1   = (const float*)d_in[10];
    const float* v1   = (const float*)d_in[11];
    const float* g2   = (const float*)d_in[12];
    const float* be2  = (const float*)d_in[13];
    const float* m2   = (const float*)d_in[14];
    const float* v2   = (const float*)d_in[15];
    const float* Wc   = (const float*)d_in[16];
    const float* bc   = (const float*)d_in[17];
    float* out = (float*)d_out;

    // Workspace: cnt [N] | agg [N*64] (layer1 then layer2) | t1 [N*64] | r1 [N*64]
    char* ws = (char*)d_ws;
    float* cnt = (float*)ws;
    float* agg = (float*)(ws + (size_t)N_NODES * sizeof(float));
    float* t1  = agg + (size_t)N_NODES * 64;
    float* r1  = t1  + (size_t)N_NODES * 64;

    const int* src = eidx;
    const int* dst = eidx + N_EDGES;

    const int edgeGrid  = (N_EDGES * 16) / 256;            // 100000 blocks
    const int node1Grid = (N_NODES + 63) / 64;             // 1563
    const int node2Grid = (N_NODES * 64 + 255) / 256;      // 25000

    // zero cnt + agg (contiguous)
    hipMemsetAsync(ws, 0, (size_t)N_NODES * sizeof(float) * 65, stream);

    edge_agg16<<<edgeGrid, 256, 0, stream>>>((const float4*)x, src, dst, agg, cnt, N_EDGES);

    node1_kernel<<<node1Grid, 256, 0, stream>>>(x, agg, cnt, W1l, b1l, W1r,
                                                g1, be1, m1, v1, W2l, W2r, t1, r1);

    hipMemsetAsync(agg, 0, (size_t)N_NODES * 64 * sizeof(float), stream);

    edge_agg16<<<edgeGrid, 256, 0, stream>>>((const float4*)t1, src, dst, agg, nullptr, N_EDGES);

    node2_kernel<<<node2Grid, 256, 0, stream>>>(agg, r1, cnt, b2l,
                                                g2, be2, m2, v2, Wc, bc, out);
}

// Round 3
// 773.310 us; speedup vs baseline: 4.0256x; 4.0256x over previous
//
#include <hip/hip_runtime.h>
#include <math.h>

#define N_NODES 100000
#define IN_DIM 64
#define HID 128
#define HID2 64
#define N_EDGES 1600000
#define BN_EPS 1e-5f

#define NB_SCAN 391   // ceil(100000/256)

// ---------------------------------------------------------------------------
// CSR build step 1: in-degree histogram (int atomics on 400 KB, L2-resident)
// ---------------------------------------------------------------------------
__global__ __launch_bounds__(256) void hist_kernel(
    const int* __restrict__ dst, int* __restrict__ deg)
{
    int e = blockIdx.x * 256 + threadIdx.x;
    if (e < N_EDGES) atomicAdd(&deg[dst[e]], 1);
}

// ---------------------------------------------------------------------------
// CSR build step 2a: per-256-chunk exclusive scan (local), emit chunk totals
// ---------------------------------------------------------------------------
__global__ __launch_bounds__(256) void scan_chunks(
    const int* __restrict__ deg, int* __restrict__ rowStart,
    int* __restrict__ chunkSum)
{
    __shared__ int s[256];
    int i = blockIdx.x * 256 + threadIdx.x;
    int v = (i < N_NODES) ? deg[i] : 0;
    s[threadIdx.x] = v;
    __syncthreads();
    #pragma unroll
    for (int off = 1; off < 256; off <<= 1) {
        int t = (threadIdx.x >= off) ? s[threadIdx.x - off] : 0;
        __syncthreads();
        s[threadIdx.x] += t;
        __syncthreads();
    }
    if (i < N_NODES) rowStart[i] = s[threadIdx.x] - v;   // chunk-local exclusive
    if (threadIdx.x == 255) chunkSum[blockIdx.x] = s[255];
}

// ---------------------------------------------------------------------------
// CSR build step 2b: exclusive scan of the 391 chunk totals (one block)
// ---------------------------------------------------------------------------
__global__ __launch_bounds__(512) void scan_sums(int* __restrict__ chunkSum)
{
    __shared__ int s[512];
    int t = threadIdx.x;
    int v = (t < NB_SCAN) ? chunkSum[t] : 0;
    s[t] = v;
    __syncthreads();
    #pragma unroll
    for (int off = 1; off < 512; off <<= 1) {
        int u = (t >= off) ? s[t - off] : 0;
        __syncthreads();
        s[t] += u;
        __syncthreads();
    }
    if (t < NB_SCAN) chunkSum[t] = s[t] - v;             // exclusive
}

// ---------------------------------------------------------------------------
// CSR build step 2c: add chunk offsets; init cursor; set rowStart[N]=E
// ---------------------------------------------------------------------------
__global__ __launch_bounds__(256) void add_offsets(
    int* __restrict__ rowStart, const int* __restrict__ chunkSum,
    int* __restrict__ cursor)
{
    int i = blockIdx.x * 256 + threadIdx.x;
    if (i < N_NODES) {
        int v = rowStart[i] + chunkSum[blockIdx.x];
        rowStart[i] = v;
        cursor[i]   = v;
    }
    if (i == 0) rowStart[N_NODES] = N_EDGES;
}

// ---------------------------------------------------------------------------
// CSR build step 3: scatter src ids into dst-sorted order
// ---------------------------------------------------------------------------
__global__ __launch_bounds__(256) void scatter_kernel(
    const int* __restrict__ src, const int* __restrict__ dst,
    int* __restrict__ cursor, int* __restrict__ sortedSrc)
{
    int e = blockIdx.x * 256 + threadIdx.x;
    if (e < N_EDGES) {
        int pos = atomicAdd(&cursor[dst[e]], 1);
        sortedSrc[pos] = src[e];
    }
}

// ---------------------------------------------------------------------------
// Aggregation by gather: one wave per node, lane = feature.
//   mean[n][lane] = (1/max(deg,1)) * sum_{j in row(n)} feat[sortedSrc[j]][lane]
// Each edge-row read is a coalesced 256 B load from a 25.6 MB (L3-resident)
// table. 4-deep unroll for MLP. No atomics.
// ---------------------------------------------------------------------------
__global__ __launch_bounds__(256) void gather_mean(
    const float* __restrict__ feat,      // [N,64]
    const int* __restrict__ rowStart,    // [N+1]
    const int* __restrict__ sortedSrc,   // [E]
    float* __restrict__ mean)            // [N,64]
{
    int node = (int)((blockIdx.x * 256u + threadIdx.x) >> 6);
    int lane = threadIdx.x & 63;
    if (node >= N_NODES) return;
    int b = rowStart[node];
    int e = rowStart[node + 1];
    float a0 = 0.f, a1 = 0.f, a2 = 0.f, a3 = 0.f;
    int j = b;
    for (; j + 4 <= e; j += 4) {
        int s0 = sortedSrc[j + 0];
        int s1 = sortedSrc[j + 1];
        int s2 = sortedSrc[j + 2];
        int s3 = sortedSrc[j + 3];
        a0 += feat[(size_t)s0 * 64 + lane];
        a1 += feat[(size_t)s1 * 64 + lane];
        a2 += feat[(size_t)s2 * 64 + lane];
        a3 += feat[(size_t)s3 * 64 + lane];
    }
    for (; j < e; ++j) a0 += feat[(size_t)sortedSrc[j] * 64 + lane];
    float sum = (a0 + a1) + (a2 + a3);
    float inv = 1.0f / fmaxf((float)(e - b), 1.0f);
    mean[(size_t)node * 64 + lane] = sum * inv;
}

// ---------------------------------------------------------------------------
// node1: per block of 64 nodes (256 threads = 4 waves):
//   h1 = relu(bn1(mean@W1_l + b1_l + x@W1_r))   (LDS only)
//   t1 = h1@W2_l ;  r1 = h1@W2_r
// ---------------------------------------------------------------------------
__global__ __launch_bounds__(256, 2) void node1_kernel(
    const float* __restrict__ x,      // [N,64]
    const float* __restrict__ mean,   // [N,64]
    const float* __restrict__ W1l,    // [64,128]
    const float* __restrict__ b1l,    // [128]
    const float* __restrict__ W1r,    // [64,128]
    const float* __restrict__ g1, const float* __restrict__ be1,
    const float* __restrict__ m1, const float* __restrict__ v1,
    const float* __restrict__ W2l,    // [128,64]
    const float* __restrict__ W2r,    // [128,64]
    float* __restrict__ t1,           // [N,64]
    float* __restrict__ r1)           // [N,64]
{
    __shared__ float sm[64][65];   // mean tile   (reused for t1 out-tile)
    __shared__ float sx[64][65];   // x tile      (reused for r1 out-tile)
    __shared__ float sh[64][129];  // h1 tile

    const int n0   = blockIdx.x * 64;
    const int t    = threadIdx.x;
    const int wave = t >> 6;
    const int lane = t & 63;

    // ---- stage: thread t handles node n0 + t/4, quad q = t&3 (16 floats) ----
    {
        const int r = t >> 2;
        const int q = t & 3;
        const int nn = n0 + r;
        if (nn < N_NODES) {
            const float4* a4 = (const float4*)(mean + (size_t)nn * 64);
            const float4* x4 = (const float4*)(x    + (size_t)nn * 64);
            #pragma unroll
            for (int i = 0; i < 4; ++i) {
                float4 av = a4[q * 4 + i];
                float4 xv = x4[q * 4 + i];
                int kb = q * 16 + i * 4;
                sm[r][kb + 0] = av.x; sm[r][kb + 1] = av.y;
                sm[r][kb + 2] = av.z; sm[r][kb + 3] = av.w;
                sx[r][kb + 0] = xv.x; sx[r][kb + 1] = xv.y;
                sx[r][kb + 2] = xv.z; sx[r][kb + 3] = xv.w;
            }
        } else {
            #pragma unroll
            for (int i = 0; i < 16; ++i) {
                sm[r][q * 16 + i] = 0.0f;
                sx[r][q * 16 + i] = 0.0f;
            }
        }
    }
    __syncthreads();

    // ---- h1; wave w owns output slice [32w, 32w+32) ----
    {
        const int jb = wave * 32;
        float acc[32];
        #pragma unroll
        for (int i = 0; i < 32; ++i) acc[i] = b1l[jb + i];
        #pragma unroll 2
        for (int k = 0; k < 64; ++k) {
            float mk = sm[lane][k];
            float xk = sx[lane][k];
            const float* wl = &W1l[k * HID + jb];
            const float* wr = &W1r[k * HID + jb];
            #pragma unroll
            for (int i = 0; i < 32; ++i) {
                acc[i] = fmaf(mk, wl[i], acc[i]);
                acc[i] = fmaf(xk, wr[i], acc[i]);
            }
        }
        #pragma unroll
        for (int i = 0; i < 32; ++i) {
            int j = jb + i;
            float s = g1[j] * rsqrtf(v1[j] + BN_EPS);
            sh[lane][j] = fmaxf((acc[i] - m1[j]) * s + be1[j], 0.0f);
        }
    }
    __syncthreads();

    // ---- t1 (waves 0,1) / r1 (waves 2,3) ----
    {
        const float* W = (wave < 2) ? W2l : W2r;
        const int ob = (wave & 1) * 32;
        float acc[32];
        #pragma unroll
        for (int i = 0; i < 32; ++i) acc[i] = 0.0f;
        #pragma unroll 2
        for (int k = 0; k < 128; ++k) {
            float hk = sh[lane][k];
            const float* wr = &W[k * HID2 + ob];
            #pragma unroll
            for (int i = 0; i < 32; ++i) acc[i] = fmaf(hk, wr[i], acc[i]);
        }
        __syncthreads();
        float* Tt = (wave < 2) ? &sm[0][0] : &sx[0][0];
        #pragma unroll
        for (int i = 0; i < 32; ++i) Tt[lane * 65 + ob + i] = acc[i];
    }
    __syncthreads();

    // ---- coalesced write of t1/r1 tiles ----
    {
        const int r = t >> 2;
        const int q = t & 3;
        const int nn = n0 + r;
        if (nn < N_NODES) {
            #pragma unroll
            for (int i = 0; i < 4; ++i) {
                int kb = q * 16 + i * 4;
                float4 tv = make_float4(sm[r][kb], sm[r][kb + 1], sm[r][kb + 2], sm[r][kb + 3]);
                float4 rv = make_float4(sx[r][kb], sx[r][kb + 1], sx[r][kb + 2], sx[r][kb + 3]);
                *(float4*)(t1 + (size_t)nn * 64 + kb) = tv;
                *(float4*)(r1 + (size_t)nn * 64 + kb) = rv;
            }
        }
    }
}

// ---------------------------------------------------------------------------
// node2: one wave per node; elementwise BN/ReLU + 2-logit reduce.
//   h2 = relu(bn2(mean2 + b2l + r1));  out = h2@Wc + bc
// ---------------------------------------------------------------------------
__global__ __launch_bounds__(256) void node2_kernel(
    const float* __restrict__ mean2,  // [N,64]  mean of t1 over in-edges
    const float* __restrict__ r1,     // [N,64]  h1@W2_r
    const float* __restrict__ b2l,    // [64]
    const float* __restrict__ g2, const float* __restrict__ be2,
    const float* __restrict__ m2, const float* __restrict__ v2,
    const float* __restrict__ Wc,     // [64,2]
    const float* __restrict__ bc,     // [2]
    float* __restrict__ out)          // [N,2]
{
    int node = (int)((blockIdx.x * 256u + threadIdx.x) >> 6);
    int lane = threadIdx.x & 63;
    if (node >= N_NODES) return;

    float pre = mean2[(size_t)node * 64 + lane] + b2l[lane]
              + r1[(size_t)node * 64 + lane];
    float s  = g2[lane] * rsqrtf(v2[lane] + BN_EPS);
    float h2 = fmaxf((pre - m2[lane]) * s + be2[lane], 0.0f);

    float l0 = h2 * Wc[lane * 2 + 0];
    float l1 = h2 * Wc[lane * 2 + 1];
    #pragma unroll
    for (int off = 32; off > 0; off >>= 1) {
        l0 += __shfl_xor(l0, off);
        l1 += __shfl_xor(l1, off);
    }
    if (lane == 0) {
        out[(size_t)node * 2 + 0] = l0 + bc[0];
        out[(size_t)node * 2 + 1] = l1 + bc[1];
    }
}

// ---------------------------------------------------------------------------
extern "C" void kernel_launch(void* const* d_in, const int* in_sizes, int n_in,
                              void* d_out, int out_size, void* d_ws, size_t ws_size,
                              hipStream_t stream)
{
    const float* x    = (const float*)d_in[0];
    const int*   eidx = (const int*)d_in[1];   // [2, E]: row 0 = src, row 1 = dst
    const float* W1l  = (const float*)d_in[2];
    const float* b1l  = (const float*)d_in[3];
    const float* W1r  = (const float*)d_in[4];
    const float* W2l  = (const float*)d_in[5];
    const float* b2l  = (const float*)d_in[6];
    const float* W2r  = (const float*)d_in[7];
    const float* g1   = (const float*)d_in[8];
    const float* be1  = (const float*)d_in[9];
    const float* m1   = (const float*)d_in[10];
    const float* v1   = (const float*)d_in[11];
    const float* g2   = (const float*)d_in[12];
    const float* be2  = (const float*)d_in[13];
    const float* m2   = (const float*)d_in[14];
    const float* v2   = (const float*)d_in[15];
    const float* Wc   = (const float*)d_in[16];
    const float* bc   = (const float*)d_in[17];
    float* out = (float*)d_out;

    const int* src = eidx;
    const int* dst = eidx + N_EDGES;

    // ---- workspace layout (256 B aligned regions) ----
    char* ws = (char*)d_ws;
    size_t off = 0;
    auto alloc = [&](size_t bytes) { void* p = ws + off; off = (off + bytes + 255) & ~(size_t)255; return p; };
    int*   deg       = (int*)  alloc((size_t)N_NODES * 4);
    int*   rowStart  = (int*)  alloc((size_t)(N_NODES + 1) * 4);
    int*   cursor    = (int*)  alloc((size_t)N_NODES * 4);
    int*   chunkSum  = (int*)  alloc(512 * 4);
    int*   sortedSrc = (int*)  alloc((size_t)N_EDGES * 4);
    float* meanBuf   = (float*)alloc((size_t)N_NODES * 64 * 4);  // mean1, then mean2
    float* t1        = (float*)alloc((size_t)N_NODES * 64 * 4);
    float* r1        = (float*)alloc((size_t)N_NODES * 64 * 4);

    const int edgeGrid  = (N_EDGES + 255) / 256;        // 6250
    const int nodeWaveGrid = (N_NODES * 64 + 255) / 256; // 25000 (wave per node)
    const int node1Grid = (N_NODES + 63) / 64;           // 1563

    // ---- CSR build ----
    hipMemsetAsync(deg, 0, (size_t)N_NODES * 4, stream);
    hist_kernel   <<<edgeGrid, 256, 0, stream>>>(dst, deg);
    scan_chunks   <<<NB_SCAN, 256, 0, stream>>>(deg, rowStart, chunkSum);
    scan_sums     <<<1, 512, 0, stream>>>(chunkSum);
    add_offsets   <<<NB_SCAN, 256, 0, stream>>>(rowStart, chunkSum, cursor);
    scatter_kernel<<<edgeGrid, 256, 0, stream>>>(src, dst, cursor, sortedSrc);

    // ---- layer 1 ----
    gather_mean <<<nodeWaveGrid, 256, 0, stream>>>(x, rowStart, sortedSrc, meanBuf);
    node1_kernel<<<node1Grid, 256, 0, stream>>>(x, meanBuf, W1l, b1l, W1r,
                                                g1, be1, m1, v1, W2l, W2r, t1, r1);

    // ---- layer 2 (meanBuf reused for mean of t1) ----
    gather_mean <<<nodeWaveGrid, 256, 0, stream>>>(t1, rowStart, sortedSrc, meanBuf);
    node2_kernel<<<nodeWaveGrid, 256, 0, stream>>>(meanBuf, r1, b2l,
                                                   g2, be2, m2, v2, Wc, bc, out);
}

// Round 4
// 512.611 us; speedup vs baseline: 6.0729x; 1.5086x over previous
//
#include <hip/hip_runtime.h>
#include <math.h>

#define N_NODES 100000
#define IN_DIM 64
#define HID 128
#define HID2 64
#define N_EDGES 1600000
#define BN_EPS 1e-5f

#define NB_SCAN 391   // ceil(100000/256)

// ---------------------------------------------------------------------------
// CSR build step 1: in-degree histogram (int atomics on 400 KB, L2-resident)
// ---------------------------------------------------------------------------
__global__ __launch_bounds__(256) void hist_kernel(
    const int* __restrict__ dst, int* __restrict__ deg)
{
    int e = blockIdx.x * 256 + threadIdx.x;
    if (e < N_EDGES) atomicAdd(&deg[dst[e]], 1);
}

// ---------------------------------------------------------------------------
// CSR build step 2a: per-256-chunk exclusive scan (local), emit chunk totals
// ---------------------------------------------------------------------------
__global__ __launch_bounds__(256) void scan_chunks(
    const int* __restrict__ deg, int* __restrict__ rowStart,
    int* __restrict__ chunkSum)
{
    __shared__ int s[256];
    int i = blockIdx.x * 256 + threadIdx.x;
    int v = (i < N_NODES) ? deg[i] : 0;
    s[threadIdx.x] = v;
    __syncthreads();
    #pragma unroll
    for (int off = 1; off < 256; off <<= 1) {
        int t = (threadIdx.x >= off) ? s[threadIdx.x - off] : 0;
        __syncthreads();
        s[threadIdx.x] += t;
        __syncthreads();
    }
    if (i < N_NODES) rowStart[i] = s[threadIdx.x] - v;   // chunk-local exclusive
    if (threadIdx.x == 255) chunkSum[blockIdx.x] = s[255];
}

// ---------------------------------------------------------------------------
// CSR build step 2b: exclusive scan of the 391 chunk totals (one block)
// ---------------------------------------------------------------------------
__global__ __launch_bounds__(512) void scan_sums(int* __restrict__ chunkSum)
{
    __shared__ int s[512];
    int t = threadIdx.x;
    int v = (t < NB_SCAN) ? chunkSum[t] : 0;
    s[t] = v;
    __syncthreads();
    #pragma unroll
    for (int off = 1; off < 512; off <<= 1) {
        int u = (t >= off) ? s[t - off] : 0;
        __syncthreads();
        s[t] += u;
        __syncthreads();
    }
    if (t < NB_SCAN) chunkSum[t] = s[t] - v;             // exclusive
}

// ---------------------------------------------------------------------------
// CSR build step 2c: add chunk offsets; init cursor; set rowStart[N]=E
// ---------------------------------------------------------------------------
__global__ __launch_bounds__(256) void add_offsets(
    int* __restrict__ rowStart, const int* __restrict__ chunkSum,
    int* __restrict__ cursor)
{
    int i = blockIdx.x * 256 + threadIdx.x;
    if (i < N_NODES) {
        int v = rowStart[i] + chunkSum[blockIdx.x];
        rowStart[i] = v;
        cursor[i]   = v;
    }
    if (i == 0) rowStart[N_NODES] = N_EDGES;
}

// ---------------------------------------------------------------------------
// CSR build step 3: scatter src ids into dst-sorted order
// ---------------------------------------------------------------------------
__global__ __launch_bounds__(256) void scatter_kernel(
    const int* __restrict__ src, const int* __restrict__ dst,
    int* __restrict__ cursor, int* __restrict__ sortedSrc)
{
    int e = blockIdx.x * 256 + threadIdx.x;
    if (e < N_EDGES) {
        int pos = atomicAdd(&cursor[dst[e]], 1);
        sortedSrc[pos] = src[e];
    }
}

// ---------------------------------------------------------------------------
// Aggregation by gather: one wave per node, lane = feature (64-wide rows).
// ---------------------------------------------------------------------------
__global__ __launch_bounds__(256) void gather_mean(
    const float* __restrict__ feat,      // [N,64]
    const int* __restrict__ rowStart,    // [N+1]
    const int* __restrict__ sortedSrc,   // [E]
    float* __restrict__ mean)            // [N,64]
{
    int node = (int)((blockIdx.x * 256u + threadIdx.x) >> 6);
    int lane = threadIdx.x & 63;
    if (node >= N_NODES) return;
    int b = rowStart[node];
    int e = rowStart[node + 1];
    float a0 = 0.f, a1 = 0.f, a2 = 0.f, a3 = 0.f;
    int j = b;
    for (; j + 4 <= e; j += 4) {
        int s0 = sortedSrc[j + 0];
        int s1 = sortedSrc[j + 1];
        int s2 = sortedSrc[j + 2];
        int s3 = sortedSrc[j + 3];
        a0 += feat[(size_t)s0 * 64 + lane];
        a1 += feat[(size_t)s1 * 64 + lane];
        a2 += feat[(size_t)s2 * 64 + lane];
        a3 += feat[(size_t)s3 * 64 + lane];
    }
    for (; j < e; ++j) a0 += feat[(size_t)sortedSrc[j] * 64 + lane];
    float sum = (a0 + a1) + (a2 + a3);
    float inv = 1.0f / fmaxf((float)(e - b), 1.0f);
    mean[(size_t)node * 64 + lane] = sum * inv;
}

// ---------------------------------------------------------------------------
// gemm128: per block, C[128 nodes][128 j] = A1@Wtop + A2@Wbot (+epilogue).
//   A1,A2: [N,64-ish] row-major slices (K halves), stride sA floats.
//   W row k (0..127), j-half h: Wsel[k>=64][h] + (k&63)*sW  (64 floats).
//   out: j<64 -> out0, j>=64 -> out1, row stride sOut floats.
//   EPI=1: val = relu( (acc+bias[j]-mu[j])*g[j]*rsqrt(var[j]+eps) + be[j] )
// LDS: A transposed [k][n] (64KB) + W [k][132] padded (67.6KB) = 130KB.
// Threads: 4 waves in 2x2 tile grid; lane computes 8 nodes x 8 outputs.
// Main loop per k: 4x ds_read_b128 (8-lane broadcast, <=2-way banks) + 64 FMA.
// ---------------------------------------------------------------------------
template<int EPI>
__global__ __launch_bounds__(256) void gemm128(
    const float* __restrict__ A1, const float* __restrict__ A2, int sA,
    const float* __restrict__ W00, const float* __restrict__ W01,
    const float* __restrict__ W10, const float* __restrict__ W11, int sW,
    float* __restrict__ out0, float* __restrict__ out1, int sOut,
    const float* __restrict__ bias,
    const float* __restrict__ g, const float* __restrict__ be,
    const float* __restrict__ mu, const float* __restrict__ var)
{
    __shared__ float Al[128][128];   // [k][node]
    __shared__ float Wl[128][132];   // [k][j] (+4 pad)

    const int t  = threadIdx.x;
    const int n0 = blockIdx.x * 128;

    // ---- stage A (transpose rows -> [k][n]) ----
    {
        const int q  = t & 3;         // which 16-float chunk of the 64-wide row
        const int rl = t >> 2;        // 0..63
        #pragma unroll
        for (int p = 0; p < 2; ++p) {
            const int r  = rl + 64 * p;
            const int nn = n0 + r;
            if (nn < N_NODES) {
                const float4* p1 = (const float4*)(A1 + (size_t)nn * sA) + q * 4;
                const float4* p2 = (const float4*)(A2 + (size_t)nn * sA) + q * 4;
                #pragma unroll
                for (int i = 0; i < 4; ++i) {
                    float4 v = p1[i];
                    int k = q * 16 + i * 4;
                    Al[k+0][r] = v.x; Al[k+1][r] = v.y;
                    Al[k+2][r] = v.z; Al[k+3][r] = v.w;
                }
                #pragma unroll
                for (int i = 0; i < 4; ++i) {
                    float4 v = p2[i];
                    int k = 64 + q * 16 + i * 4;
                    Al[k+0][r] = v.x; Al[k+1][r] = v.y;
                    Al[k+2][r] = v.z; Al[k+3][r] = v.w;
                }
            } else {
                #pragma unroll
                for (int i = 0; i < 4; ++i) {
                    int k = q * 16 + i * 4;
                    #pragma unroll
                    for (int c = 0; c < 4; ++c) {
                        Al[k+c][r] = 0.f;
                        Al[64+k+c][r] = 0.f;
                    }
                }
            }
        }
    }
    // ---- stage W: thread t -> row k=t>>1, j-half h=t&1 (64 floats) ----
    {
        const int k   = t >> 1;
        const int h   = t & 1;
        const int klo = k & 63;
        const float* src = (k < 64) ? (h ? W01 : W00) : (h ? W11 : W10);
        src += (size_t)klo * sW;
        #pragma unroll
        for (int i = 0; i < 16; ++i) {
            float4 v = ((const float4*)src)[i];
            *(float4*)&Wl[k][h * 64 + i * 4] = v;
        }
    }
    __syncthreads();

    // ---- compute: wave (wn,wj) 2x2; lane: 8 nodes x 8 outputs ----
    const int w  = t >> 6, l = t & 63;
    const int n8 = (w & 1) * 64 + (l & 7) * 8;
    const int j8 = (w >> 1) * 64 + (l >> 3) * 8;

    float acc[8][8] = {};
    #pragma unroll 4
    for (int k = 0; k < 128; ++k) {
        float4 a0 = *(const float4*)&Al[k][n8];
        float4 a1 = *(const float4*)&Al[k][n8 + 4];
        float4 w0 = *(const float4*)&Wl[k][j8];
        float4 w1 = *(const float4*)&Wl[k][j8 + 4];
        float av[8] = {a0.x, a0.y, a0.z, a0.w, a1.x, a1.y, a1.z, a1.w};
        float wv[8] = {w0.x, w0.y, w0.z, w0.w, w1.x, w1.y, w1.z, w1.w};
        #pragma unroll
        for (int r = 0; r < 8; ++r)
            #pragma unroll
            for (int c = 0; c < 8; ++c)
                acc[r][c] = fmaf(av[r], wv[c], acc[r][c]);
    }

    // ---- epilogue + store ----
    const int  jloc = j8 & 63;
    float* const op = (j8 < 64) ? out0 : out1;
    float scale[8], off[8];
    if (EPI) {
        #pragma unroll
        for (int c = 0; c < 8; ++c) {
            int j = j8 + c;
            float s = g[j] * rsqrtf(var[j] + BN_EPS);
            scale[c] = s;
            off[c]   = be[j] + (bias[j] - mu[j]) * s;
        }
    }
    #pragma unroll
    for (int r = 0; r < 8; ++r) {
        int node = n0 + n8 + r;
        if (node < N_NODES) {
            float vals[8];
            #pragma unroll
            for (int c = 0; c < 8; ++c) {
                float v = acc[r][c];
                if (EPI) v = fmaxf(fmaf(v, scale[c], off[c]), 0.0f);
                vals[c] = v;
            }
            float4* dp = (float4*)(op + (size_t)node * sOut + jloc);
            dp[0] = make_float4(vals[0], vals[1], vals[2], vals[3]);
            dp[1] = make_float4(vals[4], vals[5], vals[6], vals[7]);
        }
    }
}

// ---------------------------------------------------------------------------
// node2: one wave per node; elementwise BN/ReLU + 2-logit reduce.
// ---------------------------------------------------------------------------
__global__ __launch_bounds__(256) void node2_kernel(
    const float* __restrict__ mean2,  // [N,64]
    const float* __restrict__ r1,     // [N,64]
    const float* __restrict__ b2l,    // [64]
    const float* __restrict__ g2, const float* __restrict__ be2,
    const float* __restrict__ m2, const float* __restrict__ v2,
    const float* __restrict__ Wc,     // [64,2]
    const float* __restrict__ bc,     // [2]
    float* __restrict__ out)          // [N,2]
{
    int node = (int)((blockIdx.x * 256u + threadIdx.x) >> 6);
    int lane = threadIdx.x & 63;
    if (node >= N_NODES) return;

    float pre = mean2[(size_t)node * 64 + lane] + b2l[lane]
              + r1[(size_t)node * 64 + lane];
    float s  = g2[lane] * rsqrtf(v2[lane] + BN_EPS);
    float h2 = fmaxf((pre - m2[lane]) * s + be2[lane], 0.0f);

    float l0 = h2 * Wc[lane * 2 + 0];
    float l1 = h2 * Wc[lane * 2 + 1];
    #pragma unroll
    for (int off = 32; off > 0; off >>= 1) {
        l0 += __shfl_xor(l0, off);
        l1 += __shfl_xor(l1, off);
    }
    if (lane == 0) {
        out[(size_t)node * 2 + 0] = l0 + bc[0];
        out[(size_t)node * 2 + 1] = l1 + bc[1];
    }
}

// ---------------------------------------------------------------------------
extern "C" void kernel_launch(void* const* d_in, const int* in_sizes, int n_in,
                              void* d_out, int out_size, void* d_ws, size_t ws_size,
                              hipStream_t stream)
{
    const float* x    = (const float*)d_in[0];
    const int*   eidx = (const int*)d_in[1];   // [2, E]: row 0 = src, row 1 = dst
    const float* W1l  = (const float*)d_in[2];
    const float* b1l  = (const float*)d_in[3];
    const float* W1r  = (const float*)d_in[4];
    const float* W2l  = (const float*)d_in[5];
    const float* b2l  = (const float*)d_in[6];
    const float* W2r  = (const float*)d_in[7];
    const float* g1   = (const float*)d_in[8];
    const float* be1  = (const float*)d_in[9];
    const float* m1   = (const float*)d_in[10];
    const float* v1   = (const float*)d_in[11];
    const float* g2   = (const float*)d_in[12];
    const float* be2  = (const float*)d_in[13];
    const float* m2   = (const float*)d_in[14];
    const float* v2   = (const float*)d_in[15];
    const float* Wc   = (const float*)d_in[16];
    const float* bc   = (const float*)d_in[17];
    float* out = (float*)d_out;

    const int* src = eidx;
    const int* dst = eidx + N_EDGES;

    // ---- workspace layout ----
    char* ws = (char*)d_ws;
    size_t off = 0;
    auto alloc = [&](size_t bytes) { void* p = ws + off; off = (off + bytes + 255) & ~(size_t)255; return p; };
    int*   deg       = (int*)  alloc((size_t)N_NODES * 4);
    int*   rowStart  = (int*)  alloc((size_t)(N_NODES + 1) * 4);
    int*   cursor    = (int*)  alloc((size_t)N_NODES * 4);
    int*   chunkSum  = (int*)  alloc(512 * 4);
    int*   sortedSrc = (int*)  alloc((size_t)N_EDGES * 4);
    float* bufA      = (float*)alloc((size_t)N_NODES * 64 * 4);   // mean1, then t1
    float* bufB      = (float*)alloc((size_t)N_NODES * 64 * 4);   // r1
    float* bufH      = (float*)alloc((size_t)N_NODES * 128 * 4);  // h1, then mean2

    const int edgeGrid     = (N_EDGES + 255) / 256;       // 6250
    const int nodeWaveGrid = (N_NODES * 64 + 255) / 256;  // 25000 (wave per node)
    const int gemmGrid     = (N_NODES + 127) / 128;       // 782

    // ---- CSR build ----
    hipMemsetAsync(deg, 0, (size_t)N_NODES * 4, stream);
    hist_kernel   <<<edgeGrid, 256, 0, stream>>>(dst, deg);
    scan_chunks   <<<NB_SCAN, 256, 0, stream>>>(deg, rowStart, chunkSum);
    scan_sums     <<<1, 512, 0, stream>>>(chunkSum);
    add_offsets   <<<NB_SCAN, 256, 0, stream>>>(rowStart, chunkSum, cursor);
    scatter_kernel<<<edgeGrid, 256, 0, stream>>>(src, dst, cursor, sortedSrc);

    // ---- layer 1 ----
    gather_mean<<<nodeWaveGrid, 256, 0, stream>>>(x, rowStart, sortedSrc, bufA);

    // h1 = relu(bn1(mean@W1l + b1l + x@W1r))   [N,128] -> bufH
    gemm128<1><<<gemmGrid, 256, 0, stream>>>(
        bufA, x, 64,
        W1l, W1l + 64, W1r, W1r + 64, 128,
        bufH, bufH + 64, 128,
        b1l, g1, be1, m1, v1);

    // t1 = h1@W2l -> bufA ; r1 = h1@W2r -> bufB
    gemm128<0><<<gemmGrid, 256, 0, stream>>>(
        bufH, bufH + 64, 128,
        W2l, W2r, W2l + 64 * 64, W2r + 64 * 64, 64,
        bufA, bufB, 64,
        nullptr, nullptr, nullptr, nullptr, nullptr);

    // ---- layer 2: mean of t1 -> bufH (h1 is dead) ----
    gather_mean<<<nodeWaveGrid, 256, 0, stream>>>(bufA, rowStart, sortedSrc, bufH);

    node2_kernel<<<nodeWaveGrid, 256, 0, stream>>>(bufH, bufB, b2l,
                                                   g2, be2, m2, v2, Wc, bc, out);
}